// Round 1
// 75.389 us; speedup vs baseline: 1.0054x; 1.0054x over previous
//
#include <hip/hip_runtime.h>
#include <math.h>

namespace {

constexpr int   kN       = 4096;
constexpr int   kThreads = 256;              // 4 waves/block, 2 queries/wave
constexpr int   kEPT     = kN / 64;          // 64 elements per lane
constexpr int   kGroups  = kEPT / 2;         // 32 packed f16x2 groups per lane
constexpr int   kIters   = 9;                // scaled bracket [0,32768] -> width 64 (d2 0.031)
constexpr float kM0      = 0.3f;
constexpr float kS       = 2048.f;           // d2 scale: 16*2048 = 32768 < f16 max
constexpr float kRootS   = 45.25483399593904f;  // sqrt(2048)

typedef _Float16 h2 __attribute__((ext_vector_type(2)));

// DPP wave-64 sum -> uniform scalar (SGPR via v_readlane lane 63).
// row_shr:1/2/4/8 fold each 16-lane row; row_bcast15 (row_mask 0xa) and
// row_bcast31 (row_mask 0xc) fold rows; all VALU-pipe (~4 cyc/step) instead
// of ds_permute (~40 cyc/step) that __shfl_xor(16/32) lowers to.
__device__ __forceinline__ float dppStep_(float x, int t) {
    return x + __builtin_bit_cast(float, t);
}
__device__ __forceinline__ float waveSumUniform(float x) {
    int xi;
    xi = __builtin_amdgcn_update_dpp(0, __builtin_bit_cast(int, x), 0x111, 0xf, 0xf, true);
    x  = dppStep_(x, xi);   // + row_shr:1
    xi = __builtin_amdgcn_update_dpp(0, __builtin_bit_cast(int, x), 0x112, 0xf, 0xf, true);
    x  = dppStep_(x, xi);   // + row_shr:2
    xi = __builtin_amdgcn_update_dpp(0, __builtin_bit_cast(int, x), 0x114, 0xf, 0xf, true);
    x  = dppStep_(x, xi);   // + row_shr:4
    xi = __builtin_amdgcn_update_dpp(0, __builtin_bit_cast(int, x), 0x118, 0xf, 0xf, true);
    x  = dppStep_(x, xi);   // + row_shr:8  -> lane15 of each row = row sum
    xi = __builtin_amdgcn_update_dpp(0, __builtin_bit_cast(int, x), 0x142, 0xa, 0xf, true);
    x  = dppStep_(x, xi);   // + row_bcast15 -> lane31 = rows0+1, lane63 partial
    xi = __builtin_amdgcn_update_dpp(0, __builtin_bit_cast(int, x), 0x143, 0xc, 0xf, true);
    x  = dppStep_(x, xi);   // + row_bcast31 -> lane63 = total
    return __builtin_bit_cast(float, __builtin_amdgcn_readlane(__builtin_bit_cast(int, x), 63));
}

// t = clamp(m - d, 0, 1) in ONE VOP3P instruction: v_pk_add with src1
// negated (both halves) and the clamp modifier ([0,1] float clamp).
// Semantically identical to min(max(m-d,0),1) for our finite operands, and
// used in BOTH the bisection and the final pass, so the final-pass mask at
// lo stays bitwise-consistent with T(lo), preserving T(lo) < wb <= T(hi).
// No volatile / no memory clobber -> scheduler can move it freely.
__device__ __forceinline__ h2 subClamp(h2 m, h2 d) {
    h2 r;
    asm("v_pk_add_f16 %0, %1, %2 neg_lo:[0,1] neg_hi:[0,1] clamp"
        : "=v"(r) : "v"(m), "v"(d));
    return r;
}

// Two queries (same batch) per wave: point/weight loads, ws[] pack, and the
// wb reduction shared. All reductions are DPP chains ending in a uniform
// scalar, so the bisection compare/update is pure SALU. Bisection mids are
// multiples of 64 <= 32768 -> exact in f16.
// __launch_bounds__(256, 4): pin 4 waves/SIMD (VGPR cap 128). The grid is
// exactly 4096 waves on 1024 SIMDs -> a single residency round only if 4
// waves/SIMD fit; at 3 waves/SIMD the 4th wave serializes (~1.33x stretch).
// Register arrays are 96 VGPRs; live temps fit under 128.
__global__ __launch_bounds__(kThreads, 4)
void dtm_kernel(const float* __restrict__ input,   // (B, N, 2)
                const float* __restrict__ weight,  // (B, N)
                const float* __restrict__ grid,    // (N, 2)
                float* __restrict__ out,           // (B, N)
                int nq) {
    const int lane = threadIdx.x & 63;
    const int wave = threadIdx.x >> 6;
    const int wglob = blockIdx.x * 4 + wave;     // global wave id
    const int b    = wglob >> 11;                // 2048 waves per batch
    const int wid  = wglob & 2047;
    const int i0 = wid;                          // query A
    const int i1 = wid + kN / 2;                 // query B
    if (b * kN + i1 >= nq) return;

    // Wave-uniform -> scalar loads.
    const float sgxA = kRootS * grid[2 * i0], sgyA = kRootS * grid[2 * i0 + 1];
    const float sgxB = kRootS * grid[2 * i1], sgyB = kRootS * grid[2 * i1 + 1];
    const float4* inp4 = (const float4*)(input + (size_t)b * kN * 2);
    const float4* wgt4 = (const float4*)(weight + (size_t)b * kN);

    const h2 one2 = h2{(_Float16)1.f, (_Float16)1.f};

    h2 dA[kGroups], dB[kGroups], ws[kGroups];    // 96 VGPRs; dX holds 2048*d2
    float wl = 0.f;
#pragma unroll
    for (int s = 0; s < kGroups / 2; ++s) {      // 4 elements per trip
        const int g = lane + 64 * s;
        const float4 wv = wgt4[g];
        const float4 pa = inp4[2 * g];
        const float4 pb = inp4[2 * g + 1];
        float dx, dy, e0, e1, e2, e3;
        dx = fmaf(-kRootS, pa.x, sgxA); dy = fmaf(-kRootS, pa.y, sgyA); e0 = fmaf(dy, dy, dx * dx);
        dx = fmaf(-kRootS, pa.z, sgxA); dy = fmaf(-kRootS, pa.w, sgyA); e1 = fmaf(dy, dy, dx * dx);
        dx = fmaf(-kRootS, pb.x, sgxA); dy = fmaf(-kRootS, pb.y, sgyA); e2 = fmaf(dy, dy, dx * dx);
        dx = fmaf(-kRootS, pb.z, sgxA); dy = fmaf(-kRootS, pb.w, sgyA); e3 = fmaf(dy, dy, dx * dx);
        dA[2 * s]     = h2{(_Float16)e0, (_Float16)e1};
        dA[2 * s + 1] = h2{(_Float16)e2, (_Float16)e3};
        dx = fmaf(-kRootS, pa.x, sgxB); dy = fmaf(-kRootS, pa.y, sgyB); e0 = fmaf(dy, dy, dx * dx);
        dx = fmaf(-kRootS, pa.z, sgxB); dy = fmaf(-kRootS, pa.w, sgyB); e1 = fmaf(dy, dy, dx * dx);
        dx = fmaf(-kRootS, pb.x, sgxB); dy = fmaf(-kRootS, pb.y, sgyB); e2 = fmaf(dy, dy, dx * dx);
        dx = fmaf(-kRootS, pb.z, sgxB); dy = fmaf(-kRootS, pb.w, sgyB); e3 = fmaf(dy, dy, dx * dx);
        dB[2 * s]     = h2{(_Float16)e0, (_Float16)e1};
        dB[2 * s + 1] = h2{(_Float16)e2, (_Float16)e3};
        ws[2 * s]     = h2{(_Float16)wv.x, (_Float16)wv.y};
        ws[2 * s + 1] = h2{(_Float16)wv.z, (_Float16)wv.w};
        wl = __builtin_amdgcn_fdot2(ws[2 * s],     one2, wl, false);
        wl = __builtin_amdgcn_fdot2(ws[2 * s + 1], one2, wl, false);
    }
    const float wb = kM0 * waveSumUniform(wl);   // shared by both queries

    // Two interleaved bisections; all bracket state is scalar (SALU).
    // unroll 1: keep the ~300-instr body I-cache resident instead of a
    // 9x-unrolled ~29KB stream right at the 32KB I$ edge. Inner g-loops
    // stay fully unrolled (static register-array indexing).
    float loA = 0.f, hiA = 32768.f, TloA = 0.f;
    float loB = 0.f, hiB = 32768.f, TloB = 0.f;
#pragma unroll 1
    for (int it = 0; it < kIters; ++it) {
        const float midA = 0.5f * (loA + hiA);
        const float midB = 0.5f * (loB + hiB);
        const _Float16 mAh = (_Float16)midA;     // exact (multiple of 64)
        const _Float16 mBh = (_Float16)midB;
        const h2 mA2 = h2{mAh, mAh};
        const h2 mB2 = h2{mBh, mBh};
        float a0 = 0.f, a1 = 0.f, b0 = 0.f, b1 = 0.f;
#pragma unroll
        for (int g = 0; g < kGroups; g += 2) {
            h2 tA0 = subClamp(mA2, dA[g]);
            h2 tA1 = subClamp(mA2, dA[g + 1]);
            h2 tB0 = subClamp(mB2, dB[g]);
            h2 tB1 = subClamp(mB2, dB[g + 1]);
            a0 = __builtin_amdgcn_fdot2(ws[g],     tA0, a0, false);
            a1 = __builtin_amdgcn_fdot2(ws[g + 1], tA1, a1, false);
            b0 = __builtin_amdgcn_fdot2(ws[g],     tB0, b0, false);
            b1 = __builtin_amdgcn_fdot2(ws[g + 1], tB1, b1, false);
        }
        const float TA = waveSumUniform(a0 + a1);   // two independent DPP chains
        const float TB = waveSumUniform(b0 + b1);
        if (TA >= wb) hiA = midA; else { loA = midA; TloA = TA; }   // scalar
        if (TB >= wb) hiB = midB; else { loB = midB; TloB = TB; }
    }

    // Final pass: only A-sums below lo; W comes free as Tlo (invariant Tlo < wb).
    {
        const _Float16 lAh = (_Float16)loA;      // exact
        const _Float16 lBh = (_Float16)loB;
        const h2 lA2 = h2{lAh, lAh};
        const h2 lB2 = h2{lBh, lBh};
        float A0 = 0.f, A1 = 0.f, B0 = 0.f, B1 = 0.f;
#pragma unroll
        for (int g = 0; g < kGroups; g += 2) {
            const h2 tA0 = subClamp(lA2, dA[g]);
            const h2 tA1 = subClamp(lA2, dA[g + 1]);
            const h2 tB0 = subClamp(lB2, dB[g]);
            const h2 tB1 = subClamp(lB2, dB[g + 1]);
            const h2 pA0 = dA[g] * ws[g];        // scaled d2*w <= 32768 < 65504
            const h2 pA1 = dA[g + 1] * ws[g + 1];
            const h2 pB0 = dB[g] * ws[g];
            const h2 pB1 = dB[g + 1] * ws[g + 1];
            A0 = __builtin_amdgcn_fdot2(pA0, tA0, A0, false);
            A1 = __builtin_amdgcn_fdot2(pA1, tA1, A1, false);
            B0 = __builtin_amdgcn_fdot2(pB0, tB0, B0, false);
            B1 = __builtin_amdgcn_fdot2(pB1, tB1, B1, false);
        }
        const float AA = waveSumUniform(A0 + A1);
        const float AB = waveSumUniform(B0 + B1);
        if (lane == 0) {
            const float dtmA = (AA + hiA * (wb - TloA)) * (1.f / kS);
            const float dtmB = (AB + hiB * (wb - TloB)) * (1.f / kS);
            float* ob = out + (size_t)b * kN;
            ob[i0] = sqrtf(fmaxf(dtmA, 0.f) / wb);
            ob[i1] = sqrtf(fmaxf(dtmB, 0.f) / wb);
        }
    }
}

}  // namespace

extern "C" void kernel_launch(void* const* d_in, const int* in_sizes, int n_in,
                              void* d_out, int out_size, void* d_ws, size_t ws_size,
                              hipStream_t stream) {
    const float* input  = (const float*)d_in[0];   // (B, N, 2) f32
    const float* weight = (const float*)d_in[1];   // (B, N)    f32
    const float* grid   = (const float*)d_in[2];   // (N, 2)    f32
    float* out = (float*)d_out;                    // (B, N)    f32
    const int nq = out_size;                       // B * N = 8192
    // 2 queries per wave, 4 waves per block -> nq/8 blocks (1024).
    const int blocks = (nq + 7) / 8;
    dtm_kernel<<<dim3(blocks), dim3(kThreads), 0, stream>>>(input, weight, grid, out, nq);
}

// Round 2
// 74.126 us; speedup vs baseline: 1.0226x; 1.0170x over previous
//
#include <hip/hip_runtime.h>
#include <math.h>

namespace {

constexpr int   kN         = 4096;
constexpr int   kThreads   = 256;            // 4 waves/block, 2 queries/wave
constexpr int   kGroups    = 32;             // packed f16x2 groups per lane (64 pts/lane)
constexpr int   kItersMain = 6;              // [0,4096] -> width 64
constexpr float kM0        = 0.3f;
constexpr float kS         = 2048.f;         // d2 scale: 16*2048 = 32768 < f16 max
constexpr float kRootS     = 45.25483399593904f;  // sqrt(2048)
constexpr float kSeed      = 4096.f;         // covers worst corner query (r^2 ~3130 scaled)
constexpr float kTop       = 32768.f;

typedef _Float16 h2 __attribute__((ext_vector_type(2)));
typedef float    f2 __attribute__((ext_vector_type(2)));
typedef float    f4 __attribute__((ext_vector_type(4)));

// DPP wave-64 sum -> uniform scalar (readlane 63). All VALU-pipe.
__device__ __forceinline__ float dppStep_(float x, int t) {
    return x + __builtin_bit_cast(float, t);
}
__device__ __forceinline__ float waveSumUniform(float x) {
    int xi;
    xi = __builtin_amdgcn_update_dpp(0, __builtin_bit_cast(int, x), 0x111, 0xf, 0xf, true);
    x  = dppStep_(x, xi);   // + row_shr:1
    xi = __builtin_amdgcn_update_dpp(0, __builtin_bit_cast(int, x), 0x112, 0xf, 0xf, true);
    x  = dppStep_(x, xi);   // + row_shr:2
    xi = __builtin_amdgcn_update_dpp(0, __builtin_bit_cast(int, x), 0x114, 0xf, 0xf, true);
    x  = dppStep_(x, xi);   // + row_shr:4
    xi = __builtin_amdgcn_update_dpp(0, __builtin_bit_cast(int, x), 0x118, 0xf, 0xf, true);
    x  = dppStep_(x, xi);   // + row_shr:8  -> lane15 of each row = row sum
    xi = __builtin_amdgcn_update_dpp(0, __builtin_bit_cast(int, x), 0x142, 0xa, 0xf, true);
    x  = dppStep_(x, xi);   // + row_bcast15 -> lane31 = rows0+1, lane63 partial
    xi = __builtin_amdgcn_update_dpp(0, __builtin_bit_cast(int, x), 0x143, 0xc, 0xf, true);
    x  = dppStep_(x, xi);   // + row_bcast31 -> lane63 = total
    return __builtin_bit_cast(float, __builtin_amdgcn_readlane(__builtin_bit_cast(int, x), 63));
}

// t = clamp(m - d, 0, 1) in ONE VOP3P instruction (neg on src1 + clamp mod).
// Used in bisection AND final pass -> mask at lo is bitwise-consistent with
// T(lo), preserving T(lo) < wb <= T(hi).
__device__ __forceinline__ h2 subClamp(h2 m, h2 d) {
    h2 r;
    asm("v_pk_add_f16 %0, %1, %2 neg_lo:[0,1] neg_hi:[0,1] clamp"
        : "=v"(r) : "v"(m), "v"(d));
    return r;
}

// Packed-f32 helpers: process query A (lo half) and query B (hi half)
// simultaneously. op_sel broadcasts px / py from the loaded (px,py) pair to
// both halves with no mov. Each half executes the SAME fma sequence as the
// old scalar code -> bit-identical d2 values.
__device__ __forceinline__ f2 pk_fma_bx(f2 a, f2 p, f2 c) {  // fma(a, {px,px}, c)
    f2 d;
    asm("v_pk_fma_f32 %0, %1, %2, %3 op_sel_hi:[1,0,1]"
        : "=v"(d) : "v"(a), "v"(p), "v"(c));
    return d;
}
__device__ __forceinline__ f2 pk_fma_by(f2 a, f2 p, f2 c) {  // fma(a, {py,py}, c)
    f2 d;
    asm("v_pk_fma_f32 %0, %1, %2, %3 op_sel:[0,1,0] op_sel_hi:[1,1,1]"
        : "=v"(d) : "v"(a), "v"(p), "v"(c));
    return d;
}
__device__ __forceinline__ f2 pk_mul(f2 a, f2 b) {
    f2 d; asm("v_pk_mul_f32 %0, %1, %2" : "=v"(d) : "v"(a), "v"(b)); return d;
}
__device__ __forceinline__ f2 pk_fma(f2 a, f2 b, f2 c) {
    f2 d; asm("v_pk_fma_f32 %0, %1, %2, %3" : "=v"(d) : "v"(a), "v"(b), "v"(c)); return d;
}

// One T-evaluation pass for both queries (force-inlined; arrays stay in
// registers, all indexing static).
__device__ __forceinline__ void evalT(const h2 (&dA)[kGroups], const h2 (&dB)[kGroups],
                                      const h2 (&ws)[kGroups], h2 mA2, h2 mB2,
                                      float& TA, float& TB) {
    float a0 = 0.f, a1 = 0.f, b0 = 0.f, b1 = 0.f;
#pragma unroll
    for (int g = 0; g < kGroups; g += 2) {
        h2 tA0 = subClamp(mA2, dA[g]);
        h2 tA1 = subClamp(mA2, dA[g + 1]);
        h2 tB0 = subClamp(mB2, dB[g]);
        h2 tB1 = subClamp(mB2, dB[g + 1]);
        a0 = __builtin_amdgcn_fdot2(ws[g],     tA0, a0, false);
        a1 = __builtin_amdgcn_fdot2(ws[g + 1], tA1, a1, false);
        b0 = __builtin_amdgcn_fdot2(ws[g],     tB0, b0, false);
        b1 = __builtin_amdgcn_fdot2(ws[g + 1], tB1, b1, false);
    }
    TA = waveSumUniform(a0 + a1);
    TB = waveSumUniform(b0 + b1);
}

// Two queries (same batch) per wave. Seeded bisection: T is monotone in m,
// and every query's crossing lies below 4096 (worst case = grid corner:
// 30%-mass radius^2 ~3130 scaled; quarter-disk of r=sqrt(2) fully inside the
// domain covers 39% of area > 30%, ~16-sigma margin over weight noise). So
// one eval at 4096 + 6 halvings of [0,4096] reproduces the original
// 9-iteration mid sequence bit-exactly at 7 evals. A guarded <=3-iteration
// insurance loop handles the (never-expected) fallback bracket [4096,32768]
// correctly; in the common case it breaks immediately.
__global__ __launch_bounds__(kThreads, 4)
void dtm_kernel(const float* __restrict__ input,   // (B, N, 2)
                const float* __restrict__ weight,  // (B, N)
                const float* __restrict__ grid,    // (N, 2)
                float* __restrict__ out,           // (B, N)
                int nq) {
    const int lane = threadIdx.x & 63;
    const int wave = threadIdx.x >> 6;
    const int wglob = blockIdx.x * 4 + wave;     // global wave id
    const int b    = wglob >> 11;                // 2048 waves per batch
    const int wid  = wglob & 2047;
    const int i0 = wid;                          // query A
    const int i1 = wid + kN / 2;                 // query B
    if (b * kN + i1 >= nq) return;

    // Wave-uniform -> scalar loads.
    const float sgxA = kRootS * grid[2 * i0], sgyA = kRootS * grid[2 * i0 + 1];
    const float sgxB = kRootS * grid[2 * i1], sgyB = kRootS * grid[2 * i1 + 1];
    const f4* inp4 = (const f4*)(input + (size_t)b * kN * 2);
    const f4* wgt4 = (const f4*)(weight + (size_t)b * kN);

    const h2 one2  = h2{(_Float16)1.f, (_Float16)1.f};
    const f2 negr2 = f2{-kRootS, -kRootS};
    const f2 sgx2  = f2{sgxA, sgxB};
    const f2 sgy2  = f2{sgyA, sgyB};

    h2 dA[kGroups], dB[kGroups], ws[kGroups];    // 96 VGPRs; dX holds 2048*d2
    float wl = 0.f;
#pragma unroll
    for (int s = 0; s < kGroups / 2; ++s) {      // 4 points per trip
        const int g = lane + 64 * s;
        const f4 wv  = wgt4[g];
        const f4 pa4 = inp4[2 * g];
        const f4 pb4 = inp4[2 * g + 1];
        const f2 p0 = __builtin_shufflevector(pa4, pa4, 0, 1);
        const f2 p1 = __builtin_shufflevector(pa4, pa4, 2, 3);
        const f2 p2 = __builtin_shufflevector(pb4, pb4, 0, 1);
        const f2 p3 = __builtin_shufflevector(pb4, pb4, 2, 3);
        // d2 for {A,B} per point: identical fma/mul sequence per half as the
        // old scalar path -> bit-identical values, half the instructions.
        f2 dx, dy, q0, q1, q2, q3;
        dx = pk_fma_bx(negr2, p0, sgx2); dy = pk_fma_by(negr2, p0, sgy2);
        q0 = pk_fma(dy, dy, pk_mul(dx, dx));
        dx = pk_fma_bx(negr2, p1, sgx2); dy = pk_fma_by(negr2, p1, sgy2);
        q1 = pk_fma(dy, dy, pk_mul(dx, dx));
        dx = pk_fma_bx(negr2, p2, sgx2); dy = pk_fma_by(negr2, p2, sgy2);
        q2 = pk_fma(dy, dy, pk_mul(dx, dx));
        dx = pk_fma_bx(negr2, p3, sgx2); dy = pk_fma_by(negr2, p3, sgy2);
        q3 = pk_fma(dy, dy, pk_mul(dx, dx));
        dA[2 * s]     = h2{(_Float16)q0[0], (_Float16)q1[0]};
        dA[2 * s + 1] = h2{(_Float16)q2[0], (_Float16)q3[0]};
        dB[2 * s]     = h2{(_Float16)q0[1], (_Float16)q1[1]};
        dB[2 * s + 1] = h2{(_Float16)q2[1], (_Float16)q3[1]};
        ws[2 * s]     = h2{(_Float16)wv[0], (_Float16)wv[1]};
        ws[2 * s + 1] = h2{(_Float16)wv[2], (_Float16)wv[3]};
        wl = __builtin_amdgcn_fdot2(ws[2 * s],     one2, wl, false);
        wl = __builtin_amdgcn_fdot2(ws[2 * s + 1], one2, wl, false);
    }
    const float wb = kM0 * waveSumUniform(wl);   // shared by both queries

    // Seed: one eval at 4096 replaces the original's first 3 iterations
    // (their compares are implied by monotonicity when T(4096) >= wb).
    float loA, hiA, TloA, loB, hiB, TloB;
    {
        const _Float16 sh = (_Float16)kSeed;     // 4096 exact in f16
        const h2 s2 = h2{sh, sh};
        float TA, TB;
        evalT(dA, dB, ws, s2, s2, TA, TB);
        if (TA >= wb) { loA = 0.f;   hiA = kSeed; TloA = 0.f; }
        else          { loA = kSeed; hiA = kTop;  TloA = TA;  }
        if (TB >= wb) { loB = 0.f;   hiB = kSeed; TloB = 0.f; }
        else          { loB = kSeed; hiB = kTop;  TloB = TB;  }
    }

    // Main bisection: 6 halvings. Common bracket [0,4096] -> all mids are
    // multiples of 32 (f16-exact); fallback bracket mids multiples of 64.
#pragma unroll 1
    for (int it = 0; it < kItersMain; ++it) {
        const float midA = 0.5f * (loA + hiA);
        const float midB = 0.5f * (loB + hiB);
        const _Float16 mAh = (_Float16)midA;     // exact
        const _Float16 mBh = (_Float16)midB;
        float TA, TB;
        evalT(dA, dB, ws, h2{mAh, mAh}, h2{mBh, mBh}, TA, TB);
        if (TA >= wb) hiA = midA; else { loA = midA; TloA = TA; }
        if (TB >= wb) hiB = midB; else { loB = midB; TloB = TB; }
    }

    // Insurance (fallback-bracket only): narrow width 448 -> 56. Mids may be
    // f16-inexact there, so store back the rounded value to keep the bracket
    // consistent with the evaluated threshold. Common case: immediate break.
#pragma unroll 1
    for (int e = 0; e < 3; ++e) {
        const bool wideA = (hiA - loA) > 64.5f;  // wave-uniform scalar
        const bool wideB = (hiB - loB) > 64.5f;
        if (!wideA && !wideB) break;
        float midA = 0.5f * (loA + hiA);
        float midB = 0.5f * (loB + hiB);
        const _Float16 mAh = (_Float16)midA;
        const _Float16 mBh = (_Float16)midB;
        midA = (float)mAh; midB = (float)mBh;    // consistent storeback
        float TA, TB;
        evalT(dA, dB, ws, h2{mAh, mAh}, h2{mBh, mBh}, TA, TB);
        if (wideA) { if (TA >= wb) hiA = midA; else { loA = midA; TloA = TA; } }
        if (wideB) { if (TB >= wb) hiB = midB; else { loB = midB; TloB = TB; } }
    }

    // Final pass: A-sums at lo; W comes free as Tlo (invariant Tlo < wb).
    {
        const _Float16 lAh = (_Float16)loA;      // exact (common case)
        const _Float16 lBh = (_Float16)loB;
        const h2 lA2 = h2{lAh, lAh};
        const h2 lB2 = h2{lBh, lBh};
        float A0 = 0.f, A1 = 0.f, B0 = 0.f, B1 = 0.f;
#pragma unroll
        for (int g = 0; g < kGroups; g += 2) {
            const h2 tA0 = subClamp(lA2, dA[g]);
            const h2 tA1 = subClamp(lA2, dA[g + 1]);
            const h2 tB0 = subClamp(lB2, dB[g]);
            const h2 tB1 = subClamp(lB2, dB[g + 1]);
            const h2 pA0 = dA[g] * ws[g];        // scaled d2*w <= 32768 < 65504
            const h2 pA1 = dA[g + 1] * ws[g + 1];
            const h2 pB0 = dB[g] * ws[g];
            const h2 pB1 = dB[g + 1] * ws[g + 1];
            A0 = __builtin_amdgcn_fdot2(pA0, tA0, A0, false);
            A1 = __builtin_amdgcn_fdot2(pA1, tA1, A1, false);
            B0 = __builtin_amdgcn_fdot2(pB0, tB0, B0, false);
            B1 = __builtin_amdgcn_fdot2(pB1, tB1, B1, false);
        }
        const float AA = waveSumUniform(A0 + A1);
        const float AB = waveSumUniform(B0 + B1);
        if (lane == 0) {
            const float dtmA = (AA + hiA * (wb - TloA)) * (1.f / kS);
            const float dtmB = (AB + hiB * (wb - TloB)) * (1.f / kS);
            float* ob = out + (size_t)b * kN;
            ob[i0] = sqrtf(fmaxf(dtmA, 0.f) / wb);
            ob[i1] = sqrtf(fmaxf(dtmB, 0.f) / wb);
        }
    }
}

}  // namespace

extern "C" void kernel_launch(void* const* d_in, const int* in_sizes, int n_in,
                              void* d_out, int out_size, void* d_ws, size_t ws_size,
                              hipStream_t stream) {
    const float* input  = (const float*)d_in[0];   // (B, N, 2) f32
    const float* weight = (const float*)d_in[1];   // (B, N)    f32
    const float* grid   = (const float*)d_in[2];   // (N, 2)    f32
    float* out = (float*)d_out;                    // (B, N)    f32
    const int nq = out_size;                       // B * N = 8192
    // 2 queries per wave, 4 waves per block -> nq/8 blocks (1024).
    const int blocks = (nq + 7) / 8;
    dtm_kernel<<<dim3(blocks), dim3(kThreads), 0, stream>>>(input, weight, grid, out, nq);
}

// Round 3
// 73.440 us; speedup vs baseline: 1.0321x; 1.0093x over previous
//
#include <hip/hip_runtime.h>
#include <math.h>

namespace {

constexpr int   kN         = 4096;
constexpr int   kThreads   = 256;            // 4 waves/block, 4 queries/wave
constexpr int   kGroups    = 32;             // packed f16x2 groups per lane (64 pts/lane)
constexpr int   kItersMain = 6;              // [0,4096] -> width 64
constexpr float kM0        = 0.3f;
constexpr float kS         = 2048.f;         // d2 scale: 16*2048 = 32768 < f16 max
constexpr float kRootS     = 45.25483399593904f;  // sqrt(2048)
constexpr float kSeed      = 4096.f;         // covers worst corner query (r^2 ~3130 scaled)
constexpr float kTop       = 32768.f;

typedef _Float16 h2 __attribute__((ext_vector_type(2)));
typedef float    f2 __attribute__((ext_vector_type(2)));
typedef float    f4 __attribute__((ext_vector_type(4)));

// DPP wave-64 sum -> uniform scalar (readlane 63). All VALU-pipe.
__device__ __forceinline__ float dppStep_(float x, int t) {
    return x + __builtin_bit_cast(float, t);
}
__device__ __forceinline__ float waveSumUniform(float x) {
    int xi;
    xi = __builtin_amdgcn_update_dpp(0, __builtin_bit_cast(int, x), 0x111, 0xf, 0xf, true);
    x  = dppStep_(x, xi);   // + row_shr:1
    xi = __builtin_amdgcn_update_dpp(0, __builtin_bit_cast(int, x), 0x112, 0xf, 0xf, true);
    x  = dppStep_(x, xi);   // + row_shr:2
    xi = __builtin_amdgcn_update_dpp(0, __builtin_bit_cast(int, x), 0x114, 0xf, 0xf, true);
    x  = dppStep_(x, xi);   // + row_shr:4
    xi = __builtin_amdgcn_update_dpp(0, __builtin_bit_cast(int, x), 0x118, 0xf, 0xf, true);
    x  = dppStep_(x, xi);   // + row_shr:8  -> lane15 of each row = row sum
    xi = __builtin_amdgcn_update_dpp(0, __builtin_bit_cast(int, x), 0x142, 0xa, 0xf, true);
    x  = dppStep_(x, xi);   // + row_bcast15 -> lane31 = rows0+1, lane63 partial
    xi = __builtin_amdgcn_update_dpp(0, __builtin_bit_cast(int, x), 0x143, 0xc, 0xf, true);
    x  = dppStep_(x, xi);   // + row_bcast31 -> lane63 = total
    return __builtin_bit_cast(float, __builtin_amdgcn_readlane(__builtin_bit_cast(int, x), 63));
}

// t = clamp(m - d, 0, 1) in ONE VOP3P instruction (neg on src1 + clamp mod).
// Used in bisection AND final pass -> mask at lo is bitwise-consistent with
// T(lo), preserving T(lo) < wb <= T(hi).
__device__ __forceinline__ h2 subClamp(h2 m, h2 d) {
    h2 r;
    asm("v_pk_add_f16 %0, %1, %2 neg_lo:[0,1] neg_hi:[0,1] clamp"
        : "=v"(r) : "v"(m), "v"(d));
    return r;
}

// Packed-f32 helpers: one f2 carries two queries' values. op_sel broadcasts
// px / py from the loaded (px,py) pair to both halves with no mov. Each half
// executes the SAME fma sequence as the scalar path -> bit-identical d2.
__device__ __forceinline__ f2 pk_fma_bx(f2 a, f2 p, f2 c) {  // fma(a, {px,px}, c)
    f2 d;
    asm("v_pk_fma_f32 %0, %1, %2, %3 op_sel_hi:[1,0,1]"
        : "=v"(d) : "v"(a), "v"(p), "v"(c));
    return d;
}
__device__ __forceinline__ f2 pk_fma_by(f2 a, f2 p, f2 c) {  // fma(a, {py,py}, c)
    f2 d;
    asm("v_pk_fma_f32 %0, %1, %2, %3 op_sel:[0,1,0] op_sel_hi:[1,1,1]"
        : "=v"(d) : "v"(a), "v"(p), "v"(c));
    return d;
}
__device__ __forceinline__ f2 pk_mul(f2 a, f2 b) {
    f2 d; asm("v_pk_mul_f32 %0, %1, %2" : "=v"(d) : "v"(a), "v"(b)); return d;
}
__device__ __forceinline__ f2 pk_fma(f2 a, f2 b, f2 c) {
    f2 d; asm("v_pk_fma_f32 %0, %1, %2, %3" : "=v"(d) : "v"(a), "v"(b), "v"(c)); return d;
}

// One T-evaluation pass for all four queries (force-inlined; arrays stay in
// registers, all indexing static). 8 independent fdot2 chains -> ILP enough
// for 2 waves/SIMD.
__device__ __forceinline__ void evalT4(const h2 (&dA)[kGroups], const h2 (&dB)[kGroups],
                                       const h2 (&dC)[kGroups], const h2 (&dD)[kGroups],
                                       const h2 (&ws)[kGroups],
                                       h2 mA2, h2 mB2, h2 mC2, h2 mD2,
                                       float& TA, float& TB, float& TC, float& TD) {
    float a0 = 0.f, a1 = 0.f, b0 = 0.f, b1 = 0.f;
    float c0 = 0.f, c1 = 0.f, e0 = 0.f, e1 = 0.f;
#pragma unroll
    for (int g = 0; g < kGroups; g += 2) {
        a0 = __builtin_amdgcn_fdot2(ws[g],     subClamp(mA2, dA[g]),     a0, false);
        a1 = __builtin_amdgcn_fdot2(ws[g + 1], subClamp(mA2, dA[g + 1]), a1, false);
        b0 = __builtin_amdgcn_fdot2(ws[g],     subClamp(mB2, dB[g]),     b0, false);
        b1 = __builtin_amdgcn_fdot2(ws[g + 1], subClamp(mB2, dB[g + 1]), b1, false);
        c0 = __builtin_amdgcn_fdot2(ws[g],     subClamp(mC2, dC[g]),     c0, false);
        c1 = __builtin_amdgcn_fdot2(ws[g + 1], subClamp(mC2, dC[g + 1]), c1, false);
        e0 = __builtin_amdgcn_fdot2(ws[g],     subClamp(mD2, dD[g]),     e0, false);
        e1 = __builtin_amdgcn_fdot2(ws[g + 1], subClamp(mD2, dD[g + 1]), e1, false);
    }
    TA = waveSumUniform(a0 + a1);
    TB = waveSumUniform(b0 + b1);
    TC = waveSumUniform(c0 + c1);
    TD = waveSumUniform(e0 + e1);
}

// FOUR queries (same batch) per wave: point/weight loads and the wb
// reduction amortize over 4 queries (L2 traffic halves vs 2q/wave), and the
// register arrays (160 VGPR) + temps fit the 256-VGPR budget of 2 waves/SIMD
// in ARCH VGPRs -- no AGPR split (round-2 counters showed VGPR_Count=64,
// i.e. arrays forced into AGPRs at the 128 cap, adding accvgpr moves in
// every eval pass). Grid: 2048 waves = 512 blocks = 2 blocks/CU = 2
// waves/SIMD, single residency round.
// Seeded bisection (unchanged math): T monotone in m; every query's crossing
// lies below 4096 (worst corner: 30%-mass radius^2 ~3130 scaled, ~16-sigma
// margin over weight noise). One eval at 4096 + 6 halvings of [0,4096]
// reproduces the original 9-iteration mid sequence bit-exactly at 7 evals;
// guarded insurance loop covers the never-expected fallback bracket.
__global__ __launch_bounds__(kThreads, 2)
void dtm_kernel(const float* __restrict__ input,   // (B, N, 2)
                const float* __restrict__ weight,  // (B, N)
                const float* __restrict__ grid,    // (N, 2)
                float* __restrict__ out,           // (B, N)
                int nq) {
    const int lane = threadIdx.x & 63;
    const int wave = threadIdx.x >> 6;
    const int wglob = blockIdx.x * 4 + wave;     // global wave id [0, 2048)
    const int b    = wglob >> 10;                // 1024 waves per batch
    const int wid  = wglob & 1023;
    const int i0 = wid;                          // queries A..D
    const int i1 = wid + 1024;
    const int i2 = wid + 2048;
    const int i3 = wid + 3072;
    if ((b + 1) * kN > nq) return;

    // Wave-uniform -> scalar loads.
    const float sgxA = kRootS * grid[2 * i0], sgyA = kRootS * grid[2 * i0 + 1];
    const float sgxB = kRootS * grid[2 * i1], sgyB = kRootS * grid[2 * i1 + 1];
    const float sgxC = kRootS * grid[2 * i2], sgyC = kRootS * grid[2 * i2 + 1];
    const float sgxD = kRootS * grid[2 * i3], sgyD = kRootS * grid[2 * i3 + 1];
    const f4* inp4 = (const f4*)(input + (size_t)b * kN * 2);
    const f4* wgt4 = (const f4*)(weight + (size_t)b * kN);

    const h2 one2  = h2{(_Float16)1.f, (_Float16)1.f};
    const f2 negr2 = f2{-kRootS, -kRootS};
    const f2 sgxAB = f2{sgxA, sgxB}, sgxCD = f2{sgxC, sgxD};
    const f2 sgyAB = f2{sgyA, sgyB}, sgyCD = f2{sgyC, sgyD};

    h2 dA[kGroups], dB[kGroups], dC[kGroups], dD[kGroups], ws[kGroups];  // 160 VGPRs
    float wl = 0.f;
#pragma unroll
    for (int s = 0; s < kGroups / 2; ++s) {      // 4 points per trip
        const int g = lane + 64 * s;
        const f4 wv  = wgt4[g];
        const f4 pa4 = inp4[2 * g];
        const f4 pb4 = inp4[2 * g + 1];
        const f2 p0 = __builtin_shufflevector(pa4, pa4, 0, 1);
        const f2 p1 = __builtin_shufflevector(pa4, pa4, 2, 3);
        const f2 p2 = __builtin_shufflevector(pb4, pb4, 0, 1);
        const f2 p3 = __builtin_shufflevector(pb4, pb4, 2, 3);
        // d2 for {A,B} and {C,D} per point: identical per-half fma sequence
        // as before -> bit-identical values. 2 VOP3P per point per query-pair.
        f2 dx, dy, qAB0, qAB1, qAB2, qAB3, qCD0, qCD1, qCD2, qCD3;
        dx = pk_fma_bx(negr2, p0, sgxAB); dy = pk_fma_by(negr2, p0, sgyAB);
        qAB0 = pk_fma(dy, dy, pk_mul(dx, dx));
        dx = pk_fma_bx(negr2, p0, sgxCD); dy = pk_fma_by(negr2, p0, sgyCD);
        qCD0 = pk_fma(dy, dy, pk_mul(dx, dx));
        dx = pk_fma_bx(negr2, p1, sgxAB); dy = pk_fma_by(negr2, p1, sgyAB);
        qAB1 = pk_fma(dy, dy, pk_mul(dx, dx));
        dx = pk_fma_bx(negr2, p1, sgxCD); dy = pk_fma_by(negr2, p1, sgyCD);
        qCD1 = pk_fma(dy, dy, pk_mul(dx, dx));
        dx = pk_fma_bx(negr2, p2, sgxAB); dy = pk_fma_by(negr2, p2, sgyAB);
        qAB2 = pk_fma(dy, dy, pk_mul(dx, dx));
        dx = pk_fma_bx(negr2, p2, sgxCD); dy = pk_fma_by(negr2, p2, sgyCD);
        qCD2 = pk_fma(dy, dy, pk_mul(dx, dx));
        dx = pk_fma_bx(negr2, p3, sgxAB); dy = pk_fma_by(negr2, p3, sgyAB);
        qAB3 = pk_fma(dy, dy, pk_mul(dx, dx));
        dx = pk_fma_bx(negr2, p3, sgxCD); dy = pk_fma_by(negr2, p3, sgyCD);
        qCD3 = pk_fma(dy, dy, pk_mul(dx, dx));
        dA[2 * s]     = h2{(_Float16)qAB0[0], (_Float16)qAB1[0]};
        dA[2 * s + 1] = h2{(_Float16)qAB2[0], (_Float16)qAB3[0]};
        dB[2 * s]     = h2{(_Float16)qAB0[1], (_Float16)qAB1[1]};
        dB[2 * s + 1] = h2{(_Float16)qAB2[1], (_Float16)qAB3[1]};
        dC[2 * s]     = h2{(_Float16)qCD0[0], (_Float16)qCD1[0]};
        dC[2 * s + 1] = h2{(_Float16)qCD2[0], (_Float16)qCD3[0]};
        dD[2 * s]     = h2{(_Float16)qCD0[1], (_Float16)qCD1[1]};
        dD[2 * s + 1] = h2{(_Float16)qCD2[1], (_Float16)qCD3[1]};
        ws[2 * s]     = h2{(_Float16)wv[0], (_Float16)wv[1]};
        ws[2 * s + 1] = h2{(_Float16)wv[2], (_Float16)wv[3]};
        wl = __builtin_amdgcn_fdot2(ws[2 * s],     one2, wl, false);
        wl = __builtin_amdgcn_fdot2(ws[2 * s + 1], one2, wl, false);
    }
    const float wb = kM0 * waveSumUniform(wl);   // shared by all four queries

    // Seed: one eval at 4096 replaces the original's first 3 iterations.
    float loA, hiA, TloA, loB, hiB, TloB, loC, hiC, TloC, loD, hiD, TloD;
    {
        const _Float16 sh = (_Float16)kSeed;     // 4096 exact in f16
        const h2 s2 = h2{sh, sh};
        float TA, TB, TC, TD;
        evalT4(dA, dB, dC, dD, ws, s2, s2, s2, s2, TA, TB, TC, TD);
        if (TA >= wb) { loA = 0.f;   hiA = kSeed; TloA = 0.f; }
        else          { loA = kSeed; hiA = kTop;  TloA = TA;  }
        if (TB >= wb) { loB = 0.f;   hiB = kSeed; TloB = 0.f; }
        else          { loB = kSeed; hiB = kTop;  TloB = TB;  }
        if (TC >= wb) { loC = 0.f;   hiC = kSeed; TloC = 0.f; }
        else          { loC = kSeed; hiC = kTop;  TloC = TC;  }
        if (TD >= wb) { loD = 0.f;   hiD = kSeed; TloD = 0.f; }
        else          { loD = kSeed; hiD = kTop;  TloD = TD;  }
    }

    // Main bisection: 6 halvings. Common bracket [0,4096] -> all mids are
    // multiples of 32 (f16-exact); fallback bracket mids multiples of 64.
#pragma unroll 1
    for (int it = 0; it < kItersMain; ++it) {
        const float midA = 0.5f * (loA + hiA);
        const float midB = 0.5f * (loB + hiB);
        const float midC = 0.5f * (loC + hiC);
        const float midD = 0.5f * (loD + hiD);
        const _Float16 mAh = (_Float16)midA;     // exact
        const _Float16 mBh = (_Float16)midB;
        const _Float16 mCh = (_Float16)midC;
        const _Float16 mDh = (_Float16)midD;
        float TA, TB, TC, TD;
        evalT4(dA, dB, dC, dD, ws, h2{mAh, mAh}, h2{mBh, mBh}, h2{mCh, mCh}, h2{mDh, mDh},
               TA, TB, TC, TD);
        if (TA >= wb) hiA = midA; else { loA = midA; TloA = TA; }
        if (TB >= wb) hiB = midB; else { loB = midB; TloB = TB; }
        if (TC >= wb) hiC = midC; else { loC = midC; TloC = TC; }
        if (TD >= wb) hiD = midD; else { loD = midD; TloD = TD; }
    }

    // Insurance (fallback-bracket only): narrow width 448 -> 56. Mids may be
    // f16-inexact there, so store back the rounded value to keep the bracket
    // consistent with the evaluated threshold. Common case: immediate break.
#pragma unroll 1
    for (int e = 0; e < 3; ++e) {
        const bool wideA = (hiA - loA) > 64.5f;  // wave-uniform scalar
        const bool wideB = (hiB - loB) > 64.5f;
        const bool wideC = (hiC - loC) > 64.5f;
        const bool wideD = (hiD - loD) > 64.5f;
        if (!wideA && !wideB && !wideC && !wideD) break;
        float midA = 0.5f * (loA + hiA);
        float midB = 0.5f * (loB + hiB);
        float midC = 0.5f * (loC + hiC);
        float midD = 0.5f * (loD + hiD);
        const _Float16 mAh = (_Float16)midA;
        const _Float16 mBh = (_Float16)midB;
        const _Float16 mCh = (_Float16)midC;
        const _Float16 mDh = (_Float16)midD;
        midA = (float)mAh; midB = (float)mBh;    // consistent storeback
        midC = (float)mCh; midD = (float)mDh;
        float TA, TB, TC, TD;
        evalT4(dA, dB, dC, dD, ws, h2{mAh, mAh}, h2{mBh, mBh}, h2{mCh, mCh}, h2{mDh, mDh},
               TA, TB, TC, TD);
        if (wideA) { if (TA >= wb) hiA = midA; else { loA = midA; TloA = TA; } }
        if (wideB) { if (TB >= wb) hiB = midB; else { loB = midB; TloB = TB; } }
        if (wideC) { if (TC >= wb) hiC = midC; else { loC = midC; TloC = TC; } }
        if (wideD) { if (TD >= wb) hiD = midD; else { loD = midD; TloD = TD; } }
    }

    // Final pass: A-sums at lo; W comes free as Tlo (invariant Tlo < wb).
    {
        const _Float16 lAh = (_Float16)loA;      // exact (common case)
        const _Float16 lBh = (_Float16)loB;
        const _Float16 lCh = (_Float16)loC;
        const _Float16 lDh = (_Float16)loD;
        const h2 lA2 = h2{lAh, lAh};
        const h2 lB2 = h2{lBh, lBh};
        const h2 lC2 = h2{lCh, lCh};
        const h2 lD2 = h2{lDh, lDh};
        float A0 = 0.f, A1 = 0.f, B0 = 0.f, B1 = 0.f;
        float C0 = 0.f, C1 = 0.f, D0 = 0.f, D1 = 0.f;
#pragma unroll
        for (int g = 0; g < kGroups; g += 2) {
            const h2 w0 = ws[g], w1 = ws[g + 1];
            A0 = __builtin_amdgcn_fdot2(dA[g] * w0,     subClamp(lA2, dA[g]),     A0, false);
            A1 = __builtin_amdgcn_fdot2(dA[g + 1] * w1, subClamp(lA2, dA[g + 1]), A1, false);
            B0 = __builtin_amdgcn_fdot2(dB[g] * w0,     subClamp(lB2, dB[g]),     B0, false);
            B1 = __builtin_amdgcn_fdot2(dB[g + 1] * w1, subClamp(lB2, dB[g + 1]), B1, false);
            C0 = __builtin_amdgcn_fdot2(dC[g] * w0,     subClamp(lC2, dC[g]),     C0, false);
            C1 = __builtin_amdgcn_fdot2(dC[g + 1] * w1, subClamp(lC2, dC[g + 1]), C1, false);
            D0 = __builtin_amdgcn_fdot2(dD[g] * w0,     subClamp(lD2, dD[g]),     D0, false);
            D1 = __builtin_amdgcn_fdot2(dD[g + 1] * w1, subClamp(lD2, dD[g + 1]), D1, false);
        }
        const float AA = waveSumUniform(A0 + A1);
        const float AB = waveSumUniform(B0 + B1);
        const float AC = waveSumUniform(C0 + C1);
        const float AD = waveSumUniform(D0 + D1);
        if (lane == 0) {
            const float dtmA = (AA + hiA * (wb - TloA)) * (1.f / kS);
            const float dtmB = (AB + hiB * (wb - TloB)) * (1.f / kS);
            const float dtmC = (AC + hiC * (wb - TloC)) * (1.f / kS);
            const float dtmD = (AD + hiD * (wb - TloD)) * (1.f / kS);
            float* ob = out + (size_t)b * kN;
            ob[i0] = sqrtf(fmaxf(dtmA, 0.f) / wb);
            ob[i1] = sqrtf(fmaxf(dtmB, 0.f) / wb);
            ob[i2] = sqrtf(fmaxf(dtmC, 0.f) / wb);
            ob[i3] = sqrtf(fmaxf(dtmD, 0.f) / wb);
        }
    }
}

}  // namespace

extern "C" void kernel_launch(void* const* d_in, const int* in_sizes, int n_in,
                              void* d_out, int out_size, void* d_ws, size_t ws_size,
                              hipStream_t stream) {
    const float* input  = (const float*)d_in[0];   // (B, N, 2) f32
    const float* weight = (const float*)d_in[1];   // (B, N)    f32
    const float* grid   = (const float*)d_in[2];   // (N, 2)    f32
    float* out = (float*)d_out;                    // (B, N)    f32
    const int nq = out_size;                       // B * N = 8192
    // 4 queries per wave, 4 waves per block -> nq/16 blocks (512).
    const int blocks = (nq + 15) / 16;
    dtm_kernel<<<dim3(blocks), dim3(kThreads), 0, stream>>>(input, weight, grid, out, nq);
}